// Round 10
// baseline (4121.222 us; speedup 1.0000x reference)
//
#include <hip/hip_runtime.h>
#include <math.h>

// Problem constants (fixed by setup_inputs)
#define Bn   4
#define Nn   16384
#define CINn 32
#define DIMn 256
#define Sn   2048
#define KNEI 16
#define BNEPS 1e-5f
#define MROWS (Bn * Nn)   // 65536
#define SROWS (Bn * Sn)   // 8192

#define NWORK 248                 // worker blocks
#define NBLK  (NWORK + Bn)        // 252 total blocks (<=256 CUs, 1/CU via LDS)

struct FusedSync {
    unsigned stage[8];            // stage completion counters (workers)
    unsigned prog[Bn];            // FPS progress per batch (multiples of 256)
};

// ---------------------------------------------------------------------------
// DPP max helpers (VALU pipe). Identity 0 valid: reduced values >= 0.
// ---------------------------------------------------------------------------
#define UMAX_DPP(v, ctl, rmask)                                               \
    {                                                                         \
        unsigned _o = (unsigned)__builtin_amdgcn_update_dpp(                  \
            0, (int)(v), (ctl), (rmask), 0xf, true);                          \
        (v) = ((v) > _o) ? (v) : _o;                                          \
    }
#define WAVE_UMAX64(v)                                                        \
    UMAX_DPP(v, 0x111, 0xf) UMAX_DPP(v, 0x112, 0xf) UMAX_DPP(v, 0x114, 0xf)  \
    UMAX_DPP(v, 0x118, 0xf) UMAX_DPP(v, 0x142, 0xa) UMAX_DPP(v, 0x143, 0xc)
#define U64MAX_DPP16(khi, klo, ctl)                                           \
    {                                                                         \
        unsigned _lo2 = (unsigned)__builtin_amdgcn_update_dpp(                \
            0, (int)(klo), (ctl), 0xf, 0xf, true);                            \
        unsigned _hi2 = (unsigned)__builtin_amdgcn_update_dpp(                \
            0, (int)(khi), (ctl), 0xf, 0xf, true);                            \
        const bool _g = (_hi2 > (khi)) || (_hi2 == (khi) && _lo2 > (klo));    \
        (khi) = _g ? _hi2 : (khi);                                            \
        (klo) = _g ? _lo2 : (klo);                                            \
    }

__global__ __launch_bounds__(64) void fps_zero_kernel(unsigned* __restrict__ s)
{
    if (threadIdx.x < 12) s[threadIdx.x] = 0u;
}

// ---------------------------------------------------------------------------
// 64x64 GEMM tile computed by one 256-thread team (4 teams per 1024-block).
// Barrier counts uniform across teams (act guards data ops only).
// ---------------------------------------------------------------------------
template <bool BT, bool AFF>
__device__ void gemm_team(const float* A, const float* Bm, const float* bias,
                          const float* asc, const float* ash, float* C,
                          int K, int tile, bool act, float* lAs, float* lBs,
                          int ts)
{
    const int tx = ts & 15;
    const int ty = ts >> 4;
    const int r0 = (tile >> 2) * 64;
    const int c0 = (tile & 3) * 64;
    const int rrA = ts >> 2;
    const int kkA = (ts & 3) * 4;
    float acc[4][4] = {};
    for (int kc = 0; kc < K; kc += 16) {
        if (act) {
            const float4 v = *reinterpret_cast<const float4*>(
                &A[(size_t)(r0 + rrA) * K + kc + kkA]);
            const float vv[4] = {v.x, v.y, v.z, v.w};
#pragma unroll
            for (int m = 0; m < 4; ++m) {
                float xv = vv[m];
                if (AFF) {
                    const int k = kc + kkA + m;
                    xv = fmaxf(fmaf(xv, asc[k], ash[k]), 0.0f);
                }
                lAs[(kkA + m) * 64 + rrA] = xv;
            }
            if (BT) {
                const float4 u = *reinterpret_cast<const float4*>(
                    &Bm[(size_t)(c0 + rrA) * K + kc + kkA]);
                lBs[(kkA + 0) * 64 + rrA] = u.x;
                lBs[(kkA + 1) * 64 + rrA] = u.y;
                lBs[(kkA + 2) * 64 + rrA] = u.z;
                lBs[(kkA + 3) * 64 + rrA] = u.w;
            } else {
                const int kk = ts >> 4;
                const int cc = (ts & 15) * 4;
                const float4 u = *reinterpret_cast<const float4*>(
                    &Bm[(size_t)(kc + kk) * DIMn + c0 + cc]);
                *reinterpret_cast<float4*>(&lBs[kk * 64 + cc]) = u;
            }
        }
        __syncthreads();
        if (act) {
#pragma unroll
            for (int kk = 0; kk < 16; ++kk) {
                const float4 a = *reinterpret_cast<const float4*>(&lAs[kk * 64 + ty * 4]);
                const float4 bv = *reinterpret_cast<const float4*>(&lBs[kk * 64 + tx * 4]);
                const float av[4] = {a.x, a.y, a.z, a.w};
                const float bw[4] = {bv.x, bv.y, bv.z, bv.w};
#pragma unroll
                for (int i = 0; i < 4; ++i)
#pragma unroll
                    for (int j = 0; j < 4; ++j)
                        acc[i][j] = fmaf(av[i], bw[j], acc[i][j]);
            }
        }
        __syncthreads();
    }
    if (act) {
        const int c = c0 + tx * 4;
#pragma unroll
        for (int i = 0; i < 4; ++i) {
            float4 o;
            o.x = acc[i][0] + bias[c + 0];
            o.y = acc[i][1] + bias[c + 1];
            o.z = acc[i][2] + bias[c + 2];
            o.w = acc[i][3] + bias[c + 3];
            *reinterpret_cast<float4*>(&C[(size_t)(r0 + ty * 4 + i) * DIMn + c]) = o;
        }
    }
}

__device__ inline void stage_sync(unsigned* ctr, int t)
{
    __syncthreads();
    if (t == 0) {
        __hip_atomic_fetch_add(ctr, 1u, __ATOMIC_RELEASE, __HIP_MEMORY_SCOPE_AGENT);
        while (__hip_atomic_load(ctr, __ATOMIC_ACQUIRE, __HIP_MEMORY_SCOPE_AGENT)
               < (unsigned)NWORK)
            __builtin_amdgcn_s_sleep(2);
    }
    __syncthreads();
}

// ---------------------------------------------------------------------------
// Fused kernel. Blocks 0..3: FPS v8 -- x,y pairs LDS-resident (float2[16384],
// 128KB, conflict-free ds_read_b128: proven r4), z+dist in VGPRs (52 regs,
// proven resident r4), ALL reductions via DPP on the VALU pipe (proven r7).
// This removes the per-iteration 131KB L2 re-read (r7's bound) AND the DS-pipe
// butterfly tail (r4's bound). Blocks 4..251: h-chain with 8 stage syncs,
// then per-query gather+topk streamed behind FPS progress (unchanged from r8,
// verified). Selection numerics bit-identical to reference everywhere.
// ---------------------------------------------------------------------------
__global__ __launch_bounds__(1024, 1) void fused_kernel(
    const float* __restrict__ xyz, const float* __restrict__ points,
    const float* __restrict__ fc1_w, const float* __restrict__ fc1_b,
    const float* __restrict__ conv1_w, const float* __restrict__ conv1_b,
    const float* __restrict__ conv2_w, const float* __restrict__ conv2_b,
    const float* __restrict__ bn1_g, const float* __restrict__ bn1_b,
    const float* __restrict__ bn2_g, const float* __restrict__ bn2_b,
    float* __restrict__ h0, float* __restrict__ A1, float* __restrict__ A2,
    float* __restrict__ pre, int* __restrict__ fidx,
    float* __restrict__ ps, float* __restrict__ pq, float* __restrict__ scv,
    float* __restrict__ newxyz, FusedSync* sync)
{
    __shared__ __align__(16) char smem[131072];     // fps s_xy / topk keys / gemm tiles
    __shared__ unsigned long long s_aux[33];        // fps s_wk[2][16] / topk wred+win
    __shared__ int s_nidx[KNEI];
    const int t = threadIdx.x;

    if (blockIdx.x < Bn) {
        // ================= FPS path v8 =================
#pragma clang fp contract(off)
        float2* s_xy = reinterpret_cast<float2*>(smem);               // [16384]
        unsigned long long (*s_wk)[16] =
            reinterpret_cast<unsigned long long (*)[16]>(s_aux);
        const int b = blockIdx.x;
        const int w = t >> 6;
        const int lane = t & 63;
        const float* __restrict__ px = xyz + (size_t)b * Nn * 3;
        float z[16], dist[16];
        // thread t owns points n = 2*(jp*1024+t)+par (slot s=2jp+par)
#pragma unroll
        for (int jp = 0; jp < 8; ++jp) {
            const int u = jp * 1024 + t;
            const float x0 = px[6 * u + 0];
            const float y0 = px[6 * u + 1];
            z[2 * jp + 0]  = px[6 * u + 2];
            const float x1 = px[6 * u + 3];
            const float y1 = px[6 * u + 4];
            z[2 * jp + 1]  = px[6 * u + 5];
            float4 q; q.x = x0; q.y = y0; q.z = x1; q.w = y1;
            *reinterpret_cast<float4*>(&s_xy[2 * u]) = q;   // 16B aligned
            dist[2 * jp + 0] = __builtin_huge_valf();
            dist[2 * jp + 1] = __builtin_huge_valf();
        }
#pragma unroll
        for (int s = 0; s < 16; ++s) asm volatile("" : "+v"(z[s]));
        float cx = px[0], cy = px[1], cz = px[2];
        if (t == 0) {
            fidx[b * Sn] = 0;
            newxyz[(size_t)b * Sn * 3 + 0] = cx;
            newxyz[(size_t)b * Sn * 3 + 1] = cy;
            newxyz[(size_t)b * Sn * 3 + 2] = cz;
        }
        __syncthreads();
        for (int i = 0; i < Sn - 1; ++i) {
            // ---- update 16 dists (x,y from LDS, z from VGPR) ----
            float bd = -1.0f;
#pragma unroll
            for (int jp = 0; jp < 8; ++jp) {
                const float4 q =
                    *reinterpret_cast<const float4*>(&s_xy[2 * (jp * 1024 + t)]);
                {
                    const float dx = q.x - cx;
                    const float dy = q.y - cy;
                    const float dz = z[2 * jp] - cz;
                    const float d = (dx * dx + dy * dy) + dz * dz;  // no fma
                    const float nd = fminf(dist[2 * jp], d);
                    dist[2 * jp] = nd;
                    bd = fmaxf(bd, nd);
                }
                {
                    const float dx = q.z - cx;
                    const float dy = q.w - cy;
                    const float dz = z[2 * jp + 1] - cz;
                    const float d = (dx * dx + dy * dy) + dz * dz;  // no fma
                    const float nd = fminf(dist[2 * jp + 1], d);
                    dist[2 * jp + 1] = nd;
                    bd = fmaxf(bd, nd);
                }
            }
            // recover arg: smallest n matching bd (descending s == descending n)
            unsigned bn = 0;
#pragma unroll
            for (int s = 15; s >= 0; --s)
                if (dist[s] == bd)
                    bn = 0xFFFFFFFFu -
                         (unsigned)(2 * ((s >> 1) * 1024 + t) + (s & 1));
            // ---- wave reduce via DPP (nonneg f32 bits ~ u32 order) ----
            unsigned bdu = __float_as_uint(bd);
            unsigned m = bdu;
            WAVE_UMAX64(m)
            const unsigned bdw = (unsigned)__builtin_amdgcn_readlane((int)m, 63);
            unsigned q2 = (bdu == bdw) ? bn : 0u;
            WAVE_UMAX64(q2)
            const unsigned bnw = (unsigned)__builtin_amdgcn_readlane((int)q2, 63);
            if (lane == 0)
                s_wk[i & 1][w] = ((unsigned long long)bdw << 32) | bnw;
            __syncthreads();
            // ---- cross-wave: 16 entries, u64 DPP max in lanes 0..15 ----
            const unsigned long long kk = (lane < 16) ? s_wk[i & 1][lane] : 0ull;
            unsigned klo = (unsigned)kk;
            unsigned khi = (unsigned)(kk >> 32);
            U64MAX_DPP16(khi, klo, 0x111)
            U64MAX_DPP16(khi, klo, 0x112)
            U64MAX_DPP16(khi, klo, 0x114)
            U64MAX_DPP16(khi, klo, 0x118)
            const unsigned bnf = (unsigned)__builtin_amdgcn_readlane((int)klo, 15);
            const int wu = (int)(0xFFFFFFFFu - bnf);
            const float2 cxy = s_xy[wu];          // uniform LDS read (broadcast)
            cx = cxy.x;
            cy = cxy.y;
            cz = px[3 * wu + 2];                  // uniform scalar load (L2, 4B)
            if (t == 0) {
                fidx[b * Sn + i + 1] = wu;
                newxyz[(size_t)(b * Sn + i + 1) * 3 + 0] = cx;
                newxyz[(size_t)(b * Sn + i + 1) * 3 + 1] = cy;
                newxyz[(size_t)(b * Sn + i + 1) * 3 + 2] = cz;
                if (((i + 2) & 255) == 0)
                    __hip_atomic_store(&sync->prog[b], (unsigned)(i + 2),
                                       __ATOMIC_RELEASE, __HIP_MEMORY_SCOPE_AGENT);
            }
        }
        return;
    }

    // ======================= worker path =======================
    const int wid = blockIdx.x - Bn;
    const int team = t >> 8;
    const int ts = t & 255;
    float* lAs = reinterpret_cast<float*>(smem) + team * 2048;
    float* lBs = lAs + 1024;
    float* sc1 = scv, *sh1 = scv + 256, *sc2 = scv + 512, *sh2 = scv + 768;

    // S0: fc1 -> h0 (K=32). 4096 tiles over 992 teams, 5 uniform iters.
    for (int it = 0; it < 5; ++it) {
        const int tile = it * (NWORK * 4) + wid * 4 + team;
        gemm_team<false, false>(points, fc1_w, fc1_b, nullptr, nullptr, h0,
                                CINn, tile, tile < 4096, lAs, lBs, ts);
    }
    stage_sync(&sync->stage[0], t);
    // S1: conv1 -> A1 (K=256)
    for (int it = 0; it < 5; ++it) {
        const int tile = it * (NWORK * 4) + wid * 4 + team;
        gemm_team<true, false>(h0, conv1_w, conv1_b, nullptr, nullptr, A1,
                               DIMn, tile, tile < 4096, lAs, lBs, ts);
    }
    stage_sync(&sync->stage[1], t);
    // S2: BN1 stats (slabs of 256 rows)
    for (int sb = wid; sb < 256; sb += NWORK) {
        if (t < DIMn) {
            float s = 0.0f, q = 0.0f;
            const size_t r0 = (size_t)sb * 256;
            for (int r = 0; r < 256; ++r) {
                const float v = A1[(r0 + r) * DIMn + t];
                s += v;
                q = fmaf(v, v, q);
            }
            ps[sb * DIMn + t] = s;
            pq[sb * DIMn + t] = q;
        }
    }
    stage_sync(&sync->stage[2], t);
    // S3: BN1 finalize (block 0)
    if (wid == 0 && t < DIMn) {
        float s = 0.0f, q = 0.0f;
        for (int i = 0; i < 256; ++i) { s += ps[i * DIMn + t]; q += pq[i * DIMn + t]; }
        const float invN = 1.0f / MROWS;
        const float mean = s * invN;
        const float var = q * invN - mean * mean;
        const float r = 1.0f / sqrtf(var + BNEPS);
        const float scale = bn1_g[t] * r;
        sc1[t] = scale;
        sh1[t] = bn1_b[t] - mean * scale;
    }
    stage_sync(&sync->stage[3], t);
    // S4: conv2 -> A2 (BN1+relu fused into A-load)
    for (int it = 0; it < 5; ++it) {
        const int tile = it * (NWORK * 4) + wid * 4 + team;
        gemm_team<true, true>(A1, conv2_w, conv2_b, sc1, sh1, A2,
                              DIMn, tile, tile < 4096, lAs, lBs, ts);
    }
    stage_sync(&sync->stage[4], t);
    // S5: BN2 stats
    for (int sb = wid; sb < 256; sb += NWORK) {
        if (t < DIMn) {
            float s = 0.0f, q = 0.0f;
            const size_t r0 = (size_t)sb * 256;
            for (int r = 0; r < 256; ++r) {
                const float v = A2[(r0 + r) * DIMn + t];
                s += v;
                q = fmaf(v, v, q);
            }
            ps[sb * DIMn + t] = s;
            pq[sb * DIMn + t] = q;
        }
    }
    stage_sync(&sync->stage[5], t);
    // S6: BN2 finalize
    if (wid == 0 && t < DIMn) {
        float s = 0.0f, q = 0.0f;
        for (int i = 0; i < 256; ++i) { s += ps[i * DIMn + t]; q += pq[i * DIMn + t]; }
        const float invN = 1.0f / MROWS;
        const float mean = s * invN;
        const float var = q * invN - mean * mean;
        const float r = 1.0f / sqrtf(var + BNEPS);
        const float scale = bn2_g[t] * r;
        sc2[t] = scale;
        sh2[t] = bn2_b[t] - mean * scale;
    }
    stage_sync(&sync->stage[6], t);
    // S7: h_final = h0 + relu(BN2(A2)) -> A2 (h0 preserved for points_ori)
    for (size_t idx = (size_t)wid * 1024 + t; idx < (size_t)MROWS * DIMn / 4;
         idx += (size_t)NWORK * 1024) {
        const int c4 = (int)(idx & 63);
        const float4 hv = reinterpret_cast<const float4*>(h0)[idx];
        float4 av = reinterpret_cast<float4*>(A2)[idx];
        const float4 s4 = reinterpret_cast<const float4*>(sc2)[c4];
        const float4 b4 = reinterpret_cast<const float4*>(sh2)[c4];
        av.x = hv.x + fmaxf(fmaf(av.x, s4.x, b4.x), 0.0f);
        av.y = hv.y + fmaxf(fmaf(av.y, s4.y, b4.y), 0.0f);
        av.z = hv.z + fmaxf(fmaf(av.z, s4.z, b4.z), 0.0f);
        av.w = hv.w + fmaxf(fmaf(av.w, s4.w, b4.w), 0.0f);
        reinterpret_cast<float4*>(A2)[idx] = av;
    }
    stage_sync(&sync->stage[7], t);

    // S8: per-query gather + 16-NN + maxpool, streamed behind FPS progress.
    {
#pragma clang fp contract(off)
        unsigned* s_key = reinterpret_cast<unsigned*>(smem);          // 64 KB
        const int b = wid & 3;
        const int w = t >> 6;
        const int lane = t & 63;
        const float* px = xyz + (size_t)b * Nn * 3;
        unsigned cprog = 0;
        for (int q = wid; q < SROWS; q += NWORK) {
            const int s = q >> 2;
            if (t == 0 && cprog < (unsigned)(s + 1)) {
                unsigned p;
                do {
                    p = __hip_atomic_load(&sync->prog[b], __ATOMIC_ACQUIRE,
                                          __HIP_MEMORY_SCOPE_AGENT);
                    if (p < (unsigned)(s + 1)) __builtin_amdgcn_s_sleep(8);
                } while (p < (unsigned)(s + 1));
                cprog = p;
            }
            __syncthreads();
            const int bs = b * Sn + s;
            const float qx = newxyz[(size_t)bs * 3 + 0];
            const float qy = newxyz[(size_t)bs * 3 + 1];
            const float qz = newxyz[(size_t)bs * 3 + 2];
            const float qq = (qx * qx + qy * qy) + qz * qz;
            unsigned long long mkey = ~0ull;
#pragma unroll 4
            for (int u = 0; u < 16; ++u) {
                const int n = t + (u << 10);
                const float bx = px[n * 3 + 0];
                const float by = px[n * 3 + 1];
                const float bz = px[n * 3 + 2];
                const float bb2 = (bx * bx + by * by) + bz * bz;
                const float ab = (qx * bx + qy * by) + qz * bz;
                const float d = (qq + bb2) - 2.0f * ab;   // exact reference formula
                unsigned u32 = __float_as_uint(d);
                u32 = ((int)u32 < 0) ? ~u32 : (u32 | 0x80000000u);
                s_key[n] = u32;
                const unsigned long long k =
                    ((unsigned long long)u32 << 32) | (unsigned)n;
                mkey = (k < mkey) ? k : mkey;
            }
            __syncthreads();
            for (int r = 0; r < KNEI; ++r) {
                unsigned long long k = mkey;
#pragma unroll
                for (int off = 32; off > 0; off >>= 1) {
                    const unsigned long long o = __shfl_xor(k, off);
                    k = (o < k) ? o : k;
                }
                if (lane == 0) s_aux[w] = k;
                __syncthreads();
                if (w == 0) {
                    unsigned long long kk = (lane < 16) ? s_aux[lane] : ~0ull;
#pragma unroll
                    for (int off = 8; off > 0; off >>= 1) {
                        const unsigned long long o = __shfl_xor(kk, off);
                        kk = (o < kk) ? o : kk;
                    }
                    if (lane == 0) {
                        s_aux[32] = kk;
                        s_nidx[r] = (int)(unsigned)(kk & 0xFFFFFFFFull);
                    }
                }
                __syncthreads();
                const unsigned long long wk = s_aux[32];
                if (wk == mkey) {
                    const int wn = (int)(unsigned)(wk & 0xFFFFFFFFull);
                    s_key[wn] = 0xFFFFFFFFu;
                    mkey = ~0ull;
#pragma unroll 4
                    for (int u = 0; u < 16; ++u) {
                        const int n = t + (u << 10);
                        const unsigned long long kk2 =
                            ((unsigned long long)s_key[n] << 32) | (unsigned)n;
                        mkey = (kk2 < mkey) ? kk2 : mkey;
                    }
                }
            }
            __syncthreads();
            if (t < DIMn) {
                const int fid = fidx[bs];
                const float po = h0[((size_t)b * Nn + fid) * DIMn + t];
                float m = -__builtin_huge_valf();
#pragma unroll
                for (int r = 0; r < KNEI; ++r) {
                    const int n = s_nidx[r];
                    m = fmaxf(m, A2[((size_t)b * Nn + n) * DIMn + t]);
                }
                pre[(size_t)bs * DIMn + t] = po + m;
            }
            __syncthreads();
        }
    }
}

// ---------------------------------------------------------------------------
// final BN (serial tail, ~60us): stats, finalize, apply
// ---------------------------------------------------------------------------
__global__ __launch_bounds__(256) void stats_partial(const float* __restrict__ X,
                                                     int rowsPerBlk,
                                                     float* __restrict__ ps,
                                                     float* __restrict__ pq)
{
    const int c = threadIdx.x;
    const size_t r0 = (size_t)blockIdx.x * rowsPerBlk;
    float s = 0.0f, q = 0.0f;
    for (int r = 0; r < rowsPerBlk; ++r) {
        const float v = X[(r0 + r) * DIMn + c];
        s += v;
        q = fmaf(v, v, q);
    }
    ps[blockIdx.x * DIMn + c] = s;
    pq[blockIdx.x * DIMn + c] = q;
}

__global__ __launch_bounds__(256) void bn_finalize(const float* __restrict__ ps,
                                                   const float* __restrict__ pq,
                                                   int nblk, float invN,
                                                   const float* __restrict__ g,
                                                   const float* __restrict__ bb,
                                                   float* __restrict__ sc,
                                                   float* __restrict__ sh)
{
    const int c = threadIdx.x;
    float s = 0.0f, q = 0.0f;
    for (int i = 0; i < nblk; ++i) {
        s += ps[i * DIMn + c];
        q += pq[i * DIMn + c];
    }
    const float mean = s * invN;
    const float var = q * invN - mean * mean;
    const float r = 1.0f / sqrtf(var + BNEPS);
    const float scale = g[c] * r;
    sc[c] = scale;
    sh[c] = bb[c] - mean * scale;
}

__global__ __launch_bounds__(256) void apply_bn_kernel(const float* __restrict__ pre,
                                                       const float* __restrict__ sc,
                                                       const float* __restrict__ sh,
                                                       float* __restrict__ out)
{
    const size_t i = (size_t)blockIdx.x * 256 + threadIdx.x;
    const int c4 = (int)(i & 63);
    const float4 v = reinterpret_cast<const float4*>(pre)[i];
    const float4 s4 = reinterpret_cast<const float4*>(sc)[c4];
    const float4 b4 = reinterpret_cast<const float4*>(sh)[c4];
    float4 o;
    o.x = fmaf(v.x, s4.x, b4.x);
    o.y = fmaf(v.y, s4.y, b4.y);
    o.z = fmaf(v.z, s4.z, b4.z);
    o.w = fmaf(v.w, s4.w, b4.w);
    reinterpret_cast<float4*>(out)[i] = o;
}

// ---------------------------------------------------------------------------
// Launch. ws layout: h0 0-64Mi | A1 64-128Mi | A2 128-192Mi | pre 192-200Mi |
// fidx 200Mi | ps/pq/scv/sc3/sh3 201Mi | FusedSync 203Mi.
// ---------------------------------------------------------------------------
extern "C" void kernel_launch(void* const* d_in, const int* in_sizes, int n_in,
                              void* d_out, int out_size, void* d_ws, size_t ws_size,
                              hipStream_t stream)
{
    (void)in_sizes; (void)n_in; (void)out_size; (void)ws_size;
    const float* xyz     = (const float*)d_in[0];
    const float* points  = (const float*)d_in[1];
    const float* fc1_w   = (const float*)d_in[2];
    const float* fc1_b   = (const float*)d_in[3];
    const float* conv1_w = (const float*)d_in[4];
    const float* conv1_b = (const float*)d_in[5];
    const float* conv2_w = (const float*)d_in[6];
    const float* conv2_b = (const float*)d_in[7];
    const float* bn1_g   = (const float*)d_in[8];
    const float* bn1_b   = (const float*)d_in[9];
    const float* bn2_g   = (const float*)d_in[10];
    const float* bn2_b   = (const float*)d_in[11];
    const float* bn_g    = (const float*)d_in[12];
    const float* bn_b    = (const float*)d_in[13];

    float* out = (float*)d_out;
    float* newxyz = out;                       // [4,2048,3]
    float* outpts = out + (size_t)Bn * Sn * 3; // [4,2048,256]

    char* w = (char*)d_ws;
    float* h0   = (float*)(w);
    float* A1   = (float*)(w + (64ull << 20));
    float* A2   = (float*)(w + (128ull << 20));
    float* pre  = (float*)(w + (192ull << 20));
    int*   fidx = (int*)  (w + (200ull << 20));
    float* ps   = (float*)(w + (201ull << 20));
    float* pq   = ps + 256 * 256;
    float* scv  = pq + 256 * 256;              // sc1,sh1,sc2,sh2 [4][256]
    float* sc3  = scv + 1024;
    float* sh3  = sc3 + 256;
    FusedSync* sync = (FusedSync*)(w + (203ull << 20));

    fps_zero_kernel<<<1, 64, 0, stream>>>((unsigned*)sync);
    fused_kernel<<<NBLK, 1024, 0, stream>>>(
        xyz, points, fc1_w, fc1_b, conv1_w, conv1_b, conv2_w, conv2_b,
        bn1_g, bn1_b, bn2_g, bn2_b, h0, A1, A2, pre, fidx, ps, pq, scv,
        newxyz, sync);
    stats_partial<<<64, 256, 0, stream>>>(pre, SROWS / 64, ps, pq);
    bn_finalize<<<1, 256, 0, stream>>>(ps, pq, 64, 1.0f / SROWS, bn_g, bn_b, sc3, sh3);
    apply_bn_kernel<<<(SROWS * DIMn / 4) / 256, 256, 0, stream>>>(pre, sc3, sh3, outpts);
}

// Round 11
// 3825.300 us; speedup vs baseline: 1.0774x; 1.0774x over previous
//
#include <hip/hip_runtime.h>
#include <math.h>

// Problem constants (fixed by setup_inputs)
#define Bn   4
#define Nn   16384
#define CINn 32
#define DIMn 256
#define Sn   2048
#define KNEI 16
#define BNEPS 1e-5f
#define MROWS (Bn * Nn)   // 65536
#define SROWS (Bn * Sn)   // 8192

#define NWORK 248                 // worker blocks
#define NBLK  (NWORK + Bn)        // 252 total blocks (<=256 CUs, 1/CU via LDS)

typedef float f32x2 __attribute__((ext_vector_type(2)));

struct FusedSync {
    unsigned stage[8];            // stage completion counters (workers)
    unsigned prog[Bn];            // FPS progress per batch (multiples of 256)
};

// ---------------------------------------------------------------------------
// DPP max helpers (VALU pipe). Identity 0 valid: reduced values >= 0.
// ---------------------------------------------------------------------------
#define UMAX_DPP(v, ctl, rmask)                                               \
    {                                                                         \
        unsigned _o = (unsigned)__builtin_amdgcn_update_dpp(                  \
            0, (int)(v), (ctl), (rmask), 0xf, true);                          \
        (v) = ((v) > _o) ? (v) : _o;                                          \
    }
#define WAVE_UMAX64(v)                                                        \
    UMAX_DPP(v, 0x111, 0xf) UMAX_DPP(v, 0x112, 0xf) UMAX_DPP(v, 0x114, 0xf)  \
    UMAX_DPP(v, 0x118, 0xf) UMAX_DPP(v, 0x142, 0xa) UMAX_DPP(v, 0x143, 0xc)
#define U64MAX_DPP16(khi, klo, ctl)                                           \
    {                                                                         \
        unsigned _lo2 = (unsigned)__builtin_amdgcn_update_dpp(                \
            0, (int)(klo), (ctl), 0xf, 0xf, true);                            \
        unsigned _hi2 = (unsigned)__builtin_amdgcn_update_dpp(                \
            0, (int)(khi), (ctl), 0xf, 0xf, true);                            \
        const bool _g = (_hi2 > (khi)) || (_hi2 == (khi) && _lo2 > (klo));    \
        (khi) = _g ? _hi2 : (khi);                                            \
        (klo) = _g ? _lo2 : (klo);                                            \
    }

__global__ __launch_bounds__(64) void fps_zero_kernel(unsigned* __restrict__ s)
{
    if (threadIdx.x < 12) s[threadIdx.x] = 0u;
}

// ---------------------------------------------------------------------------
// 64x64 GEMM tile computed by one 256-thread team (4 teams per 1024-block).
// Barrier counts uniform across teams (act guards data ops only).
// ---------------------------------------------------------------------------
template <bool BT, bool AFF>
__device__ void gemm_team(const float* A, const float* Bm, const float* bias,
                          const float* asc, const float* ash, float* C,
                          int K, int tile, bool act, float* lAs, float* lBs,
                          int ts)
{
    const int tx = ts & 15;
    const int ty = ts >> 4;
    const int r0 = (tile >> 2) * 64;
    const int c0 = (tile & 3) * 64;
    const int rrA = ts >> 2;
    const int kkA = (ts & 3) * 4;
    float acc[4][4] = {};
    for (int kc = 0; kc < K; kc += 16) {
        if (act) {
            const float4 v = *reinterpret_cast<const float4*>(
                &A[(size_t)(r0 + rrA) * K + kc + kkA]);
            const float vv[4] = {v.x, v.y, v.z, v.w};
#pragma unroll
            for (int m = 0; m < 4; ++m) {
                float xv = vv[m];
                if (AFF) {
                    const int k = kc + kkA + m;
                    xv = fmaxf(fmaf(xv, asc[k], ash[k]), 0.0f);
                }
                lAs[(kkA + m) * 64 + rrA] = xv;
            }
            if (BT) {
                const float4 u = *reinterpret_cast<const float4*>(
                    &Bm[(size_t)(c0 + rrA) * K + kc + kkA]);
                lBs[(kkA + 0) * 64 + rrA] = u.x;
                lBs[(kkA + 1) * 64 + rrA] = u.y;
                lBs[(kkA + 2) * 64 + rrA] = u.z;
                lBs[(kkA + 3) * 64 + rrA] = u.w;
            } else {
                const int kk = ts >> 4;
                const int cc = (ts & 15) * 4;
                const float4 u = *reinterpret_cast<const float4*>(
                    &Bm[(size_t)(kc + kk) * DIMn + c0 + cc]);
                *reinterpret_cast<float4*>(&lBs[kk * 64 + cc]) = u;
            }
        }
        __syncthreads();
        if (act) {
#pragma unroll
            for (int kk = 0; kk < 16; ++kk) {
                const float4 a = *reinterpret_cast<const float4*>(&lAs[kk * 64 + ty * 4]);
                const float4 bv = *reinterpret_cast<const float4*>(&lBs[kk * 64 + tx * 4]);
                const float av[4] = {a.x, a.y, a.z, a.w};
                const float bw[4] = {bv.x, bv.y, bv.z, bv.w};
#pragma unroll
                for (int i = 0; i < 4; ++i)
#pragma unroll
                    for (int j = 0; j < 4; ++j)
                        acc[i][j] = fmaf(av[i], bw[j], acc[i][j]);
            }
        }
        __syncthreads();
    }
    if (act) {
        const int c = c0 + tx * 4;
#pragma unroll
        for (int i = 0; i < 4; ++i) {
            float4 o;
            o.x = acc[i][0] + bias[c + 0];
            o.y = acc[i][1] + bias[c + 1];
            o.z = acc[i][2] + bias[c + 2];
            o.w = acc[i][3] + bias[c + 3];
            *reinterpret_cast<float4*>(&C[(size_t)(r0 + ty * 4 + i) * DIMn + c]) = o;
        }
    }
}

__device__ inline void stage_sync(unsigned* ctr, int t)
{
    __syncthreads();
    if (t == 0) {
        __hip_atomic_fetch_add(ctr, 1u, __ATOMIC_RELEASE, __HIP_MEMORY_SCOPE_AGENT);
        while (__hip_atomic_load(ctr, __ATOMIC_ACQUIRE, __HIP_MEMORY_SCOPE_AGENT)
               < (unsigned)NWORK)
            __builtin_amdgcn_s_sleep(2);
    }
    __syncthreads();
}

// ---------------------------------------------------------------------------
// Fused kernel. Blocks 0..3: FPS v9 --
//   * (x0,x1,y0,y1) pair-packed in LDS (128KB): float2 ext-vector update math
//     -> v_pk_mul/add_f32 (exact f32 per lane, contract off, order preserved).
//   * z,dist in VGPR pairs. ZERO global accesses in the serial loop:
//     winner z is selected during arg-recovery and published per-wave to LDS
//     alongside the reduction key (ballot+shfl find the wave winner).
//   * Outputs (fidx,newxyz) buffered in a 4KB LDS ring, flushed every 256
//     iterations right before the prog release -> no per-iter store drains.
// Blocks 4..251: h-chain with 8 stage syncs, then per-query gather+topk
// streamed behind FPS progress (unchanged from r8, verified).
// Selection numerics bit-identical to reference everywhere.
// ---------------------------------------------------------------------------
__global__ __launch_bounds__(1024, 1) void fused_kernel(
    const float* __restrict__ xyz, const float* __restrict__ points,
    const float* __restrict__ fc1_w, const float* __restrict__ fc1_b,
    const float* __restrict__ conv1_w, const float* __restrict__ conv1_b,
    const float* __restrict__ conv2_w, const float* __restrict__ conv2_b,
    const float* __restrict__ bn1_g, const float* __restrict__ bn1_b,
    const float* __restrict__ bn2_g, const float* __restrict__ bn2_b,
    float* __restrict__ h0, float* __restrict__ A1, float* __restrict__ A2,
    float* __restrict__ pre, int* __restrict__ fidx,
    float* __restrict__ ps, float* __restrict__ pq, float* __restrict__ scv,
    float* __restrict__ newxyz, FusedSync* sync)
{
    __shared__ __align__(16) char smem[131072];     // fps xy-pairs / topk keys / gemm
    __shared__ unsigned long long s_aux[33];        // fps s_wk[2][16] / topk wred+win
    __shared__ float s_wz[2][16];                   // fps per-wave winner z (parity)
    __shared__ __align__(16) float4 s_obuf[256];    // fps output ring (4KB)
    __shared__ int s_nidx[KNEI];
    const int t = threadIdx.x;

    if (blockIdx.x < Bn) {
        // ================= FPS path v9 =================
#pragma clang fp contract(off)
        float4* s_xy4 = reinterpret_cast<float4*>(smem);   // [8192] (x0,x1,y0,y1)
        unsigned long long (*s_wk)[16] =
            reinterpret_cast<unsigned long long (*)[16]>(s_aux);
        const int b = blockIdx.x;
        const int w = t >> 6;
        const int lane = t & 63;
        const float* __restrict__ px = xyz + (size_t)b * Nn * 3;
        f32x2 z2[8], dist2[8];
        // pair u = jp*1024 + t owns points 2u, 2u+1
#pragma unroll
        for (int jp = 0; jp < 8; ++jp) {
            const int u = jp * 1024 + t;
            const float2 q0 = *reinterpret_cast<const float2*>(&px[6 * u + 0]);
            const float2 q1 = *reinterpret_cast<const float2*>(&px[6 * u + 2]);
            const float2 q2 = *reinterpret_cast<const float2*>(&px[6 * u + 4]);
            float4 pk; pk.x = q0.x; pk.y = q1.y; pk.z = q0.y; pk.w = q2.x;
            s_xy4[u] = pk;                                   // (x0,x1,y0,y1)
            z2[jp] = f32x2{q1.x, q2.y};
            dist2[jp] = f32x2{__builtin_huge_valf(), __builtin_huge_valf()};
        }
#pragma unroll
        for (int p = 0; p < 8; ++p) asm volatile("" : "+v"(z2[p]));
        float cx = px[0], cy = px[1], cz = px[2];
        if (t == 0) {
            float4 o0; o0.x = cx; o0.y = cy; o0.z = cz; o0.w = __int_as_float(0);
            s_obuf[0] = o0;
        }
        __syncthreads();
        for (int i = 0; i < Sn - 1; ++i) {
            const f32x2 cx2 = {cx, cx}, cy2 = {cy, cy}, cz2 = {cz, cz};
            // ---- packed update of 8 pairs (x,y from LDS, z from VGPR) ----
            float bd = -1.0f;
#pragma unroll
            for (int jp = 0; jp < 8; ++jp) {
                const float4 q = s_xy4[jp * 1024 + t];
                const f32x2 dx = f32x2{q.x, q.y} - cx2;
                const f32x2 dy = f32x2{q.z, q.w} - cy2;
                const f32x2 dz = z2[jp] - cz2;
                const f32x2 dd = (dx * dx + dy * dy) + dz * dz;  // no fma
                const float n0 = fminf(dist2[jp].x, dd.x);
                const float n1 = fminf(dist2[jp].y, dd.y);
                dist2[jp] = f32x2{n0, n1};
                bd = fmaxf(bd, fmaxf(n0, n1));
            }
            // arg + z recovery: smallest n matching bd (descending n scan)
            unsigned bn = 0;
            float zb = 0.0f;
#pragma unroll
            for (int jp = 7; jp >= 0; --jp) {
                const unsigned n0 = 2u * (unsigned)(jp * 1024 + t);
                if (dist2[jp].y == bd) { bn = 0xFFFFFFFFu - (n0 + 1); zb = z2[jp].y; }
                if (dist2[jp].x == bd) { bn = 0xFFFFFFFFu - n0;       zb = z2[jp].x; }
            }
            // ---- wave reduce via DPP (nonneg f32 bits ~ u32 order) ----
            const unsigned bdu = __float_as_uint(bd);
            unsigned m = bdu;
            WAVE_UMAX64(m)
            const unsigned bdw = (unsigned)__builtin_amdgcn_readlane((int)m, 63);
            unsigned q2 = (bdu == bdw) ? bn : 0u;
            WAVE_UMAX64(q2)
            const unsigned bnw = (unsigned)__builtin_amdgcn_readlane((int)q2, 63);
            // winner lane's z (unique: bn embeds n)
            const unsigned long long wmask = __ballot(bdu == bdw && bn == bnw);
            const int wl = __ffsll((unsigned long long)wmask) - 1;
            const float zw = __shfl(zb, wl);
            if (lane == 0) {
                s_wk[i & 1][w] = ((unsigned long long)bdw << 32) | bnw;
                s_wz[i & 1][w] = zw;
            }
            __syncthreads();
            // ---- cross-wave: 16 entries, u64 DPP max in lanes 0..15 ----
            const unsigned long long kk = (lane < 16) ? s_wk[i & 1][lane] : 0ull;
            unsigned klo = (unsigned)kk;
            unsigned khi = (unsigned)(kk >> 32);
            U64MAX_DPP16(khi, klo, 0x111)
            U64MAX_DPP16(khi, klo, 0x112)
            U64MAX_DPP16(khi, klo, 0x114)
            U64MAX_DPP16(khi, klo, 0x118)
            const unsigned bnf = (unsigned)__builtin_amdgcn_readlane((int)klo, 15);
            const int wu = (int)(0xFFFFFFFFu - bnf);
            const int up = wu >> 1;                     // pair index
            const int ww = (up & 1023) >> 6;            // owner wave
            const float4 qw = s_xy4[up];                // uniform LDS read
            cx = (wu & 1) ? qw.y : qw.x;
            cy = (wu & 1) ? qw.w : qw.z;
            cz = s_wz[i & 1][ww];                       // from owner wave (LDS)
            if (t == 0) {
                float4 ob; ob.x = cx; ob.y = cy; ob.z = cz;
                ob.w = __int_as_float(wu);
                s_obuf[(i + 1) & 255] = ob;
            }
            // ---- flush ring + publish progress every 256 samples ----
            if (((i + 2) & 255) == 0) {
                __syncthreads();                        // ring writes visible
                const int cb = (i + 1) - 255;
                if (t < 256) {
                    const float4 v = s_obuf[t];
                    const int bs = b * Sn + cb + t;
                    newxyz[(size_t)bs * 3 + 0] = v.x;
                    newxyz[(size_t)bs * 3 + 1] = v.y;
                    newxyz[(size_t)bs * 3 + 2] = v.z;
                    fidx[bs] = __float_as_int(v.w);
                }
                __syncthreads();                        // flush stores drained
                if (t == 0)
                    __hip_atomic_store(&sync->prog[b], (unsigned)(i + 2),
                                       __ATOMIC_RELEASE, __HIP_MEMORY_SCOPE_AGENT);
            }
        }
        return;
    }

    // ======================= worker path =======================
    const int wid = blockIdx.x - Bn;
    const int team = t >> 8;
    const int ts = t & 255;
    float* lAs = reinterpret_cast<float*>(smem) + team * 2048;
    float* lBs = lAs + 1024;
    float* sc1 = scv, *sh1 = scv + 256, *sc2 = scv + 512, *sh2 = scv + 768;

    // S0: fc1 -> h0 (K=32). 4096 tiles over 992 teams, 5 uniform iters.
    for (int it = 0; it < 5; ++it) {
        const int tile = it * (NWORK * 4) + wid * 4 + team;
        gemm_team<false, false>(points, fc1_w, fc1_b, nullptr, nullptr, h0,
                                CINn, tile, tile < 4096, lAs, lBs, ts);
    }
    stage_sync(&sync->stage[0], t);
    // S1: conv1 -> A1 (K=256)
    for (int it = 0; it < 5; ++it) {
        const int tile = it * (NWORK * 4) + wid * 4 + team;
        gemm_team<true, false>(h0, conv1_w, conv1_b, nullptr, nullptr, A1,
                               DIMn, tile, tile < 4096, lAs, lBs, ts);
    }
    stage_sync(&sync->stage[1], t);
    // S2: BN1 stats (slabs of 256 rows)
    for (int sb = wid; sb < 256; sb += NWORK) {
        if (t < DIMn) {
            float s = 0.0f, q = 0.0f;
            const size_t r0 = (size_t)sb * 256;
            for (int r = 0; r < 256; ++r) {
                const float v = A1[(r0 + r) * DIMn + t];
                s += v;
                q = fmaf(v, v, q);
            }
            ps[sb * DIMn + t] = s;
            pq[sb * DIMn + t] = q;
        }
    }
    stage_sync(&sync->stage[2], t);
    // S3: BN1 finalize (block 0)
    if (wid == 0 && t < DIMn) {
        float s = 0.0f, q = 0.0f;
        for (int i = 0; i < 256; ++i) { s += ps[i * DIMn + t]; q += pq[i * DIMn + t]; }
        const float invN = 1.0f / MROWS;
        const float mean = s * invN;
        const float var = q * invN - mean * mean;
        const float r = 1.0f / sqrtf(var + BNEPS);
        const float scale = bn1_g[t] * r;
        sc1[t] = scale;
        sh1[t] = bn1_b[t] - mean * scale;
    }
    stage_sync(&sync->stage[3], t);
    // S4: conv2 -> A2 (BN1+relu fused into A-load)
    for (int it = 0; it < 5; ++it) {
        const int tile = it * (NWORK * 4) + wid * 4 + team;
        gemm_team<true, true>(A1, conv2_w, conv2_b, sc1, sh1, A2,
                              DIMn, tile, tile < 4096, lAs, lBs, ts);
    }
    stage_sync(&sync->stage[4], t);
    // S5: BN2 stats
    for (int sb = wid; sb < 256; sb += NWORK) {
        if (t < DIMn) {
            float s = 0.0f, q = 0.0f;
            const size_t r0 = (size_t)sb * 256;
            for (int r = 0; r < 256; ++r) {
                const float v = A2[(r0 + r) * DIMn + t];
                s += v;
                q = fmaf(v, v, q);
            }
            ps[sb * DIMn + t] = s;
            pq[sb * DIMn + t] = q;
        }
    }
    stage_sync(&sync->stage[5], t);
    // S6: BN2 finalize
    if (wid == 0 && t < DIMn) {
        float s = 0.0f, q = 0.0f;
        for (int i = 0; i < 256; ++i) { s += ps[i * DIMn + t]; q += pq[i * DIMn + t]; }
        const float invN = 1.0f / MROWS;
        const float mean = s * invN;
        const float var = q * invN - mean * mean;
        const float r = 1.0f / sqrtf(var + BNEPS);
        const float scale = bn2_g[t] * r;
        sc2[t] = scale;
        sh2[t] = bn2_b[t] - mean * scale;
    }
    stage_sync(&sync->stage[6], t);
    // S7: h_final = h0 + relu(BN2(A2)) -> A2 (h0 preserved for points_ori)
    for (size_t idx = (size_t)wid * 1024 + t; idx < (size_t)MROWS * DIMn / 4;
         idx += (size_t)NWORK * 1024) {
        const int c4 = (int)(idx & 63);
        const float4 hv = reinterpret_cast<const float4*>(h0)[idx];
        float4 av = reinterpret_cast<float4*>(A2)[idx];
        const float4 s4 = reinterpret_cast<const float4*>(sc2)[c4];
        const float4 b4 = reinterpret_cast<const float4*>(sh2)[c4];
        av.x = hv.x + fmaxf(fmaf(av.x, s4.x, b4.x), 0.0f);
        av.y = hv.y + fmaxf(fmaf(av.y, s4.y, b4.y), 0.0f);
        av.z = hv.z + fmaxf(fmaf(av.z, s4.z, b4.z), 0.0f);
        av.w = hv.w + fmaxf(fmaf(av.w, s4.w, b4.w), 0.0f);
        reinterpret_cast<float4*>(A2)[idx] = av;
    }
    stage_sync(&sync->stage[7], t);

    // S8: per-query gather + 16-NN + maxpool, streamed behind FPS progress.
    {
#pragma clang fp contract(off)
        unsigned* s_key = reinterpret_cast<unsigned*>(smem);          // 64 KB
        const int b = wid & 3;
        const int w = t >> 6;
        const int lane = t & 63;
        const float* px = xyz + (size_t)b * Nn * 3;
        unsigned cprog = 0;
        for (int q = wid; q < SROWS; q += NWORK) {
            const int s = q >> 2;
            if (t == 0 && cprog < (unsigned)(s + 1)) {
                unsigned p;
                do {
                    p = __hip_atomic_load(&sync->prog[b], __ATOMIC_ACQUIRE,
                                          __HIP_MEMORY_SCOPE_AGENT);
                    if (p < (unsigned)(s + 1)) __builtin_amdgcn_s_sleep(8);
                } while (p < (unsigned)(s + 1));
                cprog = p;
            }
            __syncthreads();
            const int bs = b * Sn + s;
            const float qx = newxyz[(size_t)bs * 3 + 0];
            const float qy = newxyz[(size_t)bs * 3 + 1];
            const float qz = newxyz[(size_t)bs * 3 + 2];
            const float qq = (qx * qx + qy * qy) + qz * qz;
            unsigned long long mkey = ~0ull;
#pragma unroll 4
            for (int u = 0; u < 16; ++u) {
                const int n = t + (u << 10);
                const float bx = px[n * 3 + 0];
                const float by = px[n * 3 + 1];
                const float bz = px[n * 3 + 2];
                const float bb2 = (bx * bx + by * by) + bz * bz;
                const float ab = (qx * bx + qy * by) + qz * bz;
                const float d = (qq + bb2) - 2.0f * ab;   // exact reference formula
                unsigned u32 = __float_as_uint(d);
                u32 = ((int)u32 < 0) ? ~u32 : (u32 | 0x80000000u);
                s_key[n] = u32;
                const unsigned long long k =
                    ((unsigned long long)u32 << 32) | (unsigned)n;
                mkey = (k < mkey) ? k : mkey;
            }
            __syncthreads();
            for (int r = 0; r < KNEI; ++r) {
                unsigned long long k = mkey;
#pragma unroll
                for (int off = 32; off > 0; off >>= 1) {
                    const unsigned long long o = __shfl_xor(k, off);
                    k = (o < k) ? o : k;
                }
                if (lane == 0) s_aux[w] = k;
                __syncthreads();
                if (w == 0) {
                    unsigned long long kk = (lane < 16) ? s_aux[lane] : ~0ull;
#pragma unroll
                    for (int off = 8; off > 0; off >>= 1) {
                        const unsigned long long o = __shfl_xor(kk, off);
                        kk = (o < kk) ? o : kk;
                    }
                    if (lane == 0) {
                        s_aux[32] = kk;
                        s_nidx[r] = (int)(unsigned)(kk & 0xFFFFFFFFull);
                    }
                }
                __syncthreads();
                const unsigned long long wk = s_aux[32];
                if (wk == mkey) {
                    const int wn = (int)(unsigned)(wk & 0xFFFFFFFFull);
                    s_key[wn] = 0xFFFFFFFFu;
                    mkey = ~0ull;
#pragma unroll 4
                    for (int u = 0; u < 16; ++u) {
                        const int n = t + (u << 10);
                        const unsigned long long kk2 =
                            ((unsigned long long)s_key[n] << 32) | (unsigned)n;
                        mkey = (kk2 < mkey) ? kk2 : mkey;
                    }
                }
            }
            __syncthreads();
            if (t < DIMn) {
                const int fid = fidx[bs];
                const float po = h0[((size_t)b * Nn + fid) * DIMn + t];
                float m = -__builtin_huge_valf();
#pragma unroll
                for (int r = 0; r < KNEI; ++r) {
                    const int n = s_nidx[r];
                    m = fmaxf(m, A2[((size_t)b * Nn + n) * DIMn + t]);
                }
                pre[(size_t)bs * DIMn + t] = po + m;
            }
            __syncthreads();
        }
    }
}

// ---------------------------------------------------------------------------
// final BN (serial tail, ~60us): stats, finalize, apply
// ---------------------------------------------------------------------------
__global__ __launch_bounds__(256) void stats_partial(const float* __restrict__ X,
                                                     int rowsPerBlk,
                                                     float* __restrict__ ps,
                                                     float* __restrict__ pq)
{
    const int c = threadIdx.x;
    const size_t r0 = (size_t)blockIdx.x * rowsPerBlk;
    float s = 0.0f, q = 0.0f;
    for (int r = 0; r < rowsPerBlk; ++r) {
        const float v = X[(r0 + r) * DIMn + c];
        s += v;
        q = fmaf(v, v, q);
    }
    ps[blockIdx.x * DIMn + c] = s;
    pq[blockIdx.x * DIMn + c] = q;
}

__global__ __launch_bounds__(256) void bn_finalize(const float* __restrict__ ps,
                                                   const float* __restrict__ pq,
                                                   int nblk, float invN,
                                                   const float* __restrict__ g,
                                                   const float* __restrict__ bb,
                                                   float* __restrict__ sc,
                                                   float* __restrict__ sh)
{
    const int c = threadIdx.x;
    float s = 0.0f, q = 0.0f;
    for (int i = 0; i < nblk; ++i) {
        s += ps[i * DIMn + c];
        q += pq[i * DIMn + c];
    }
    const float mean = s * invN;
    const float var = q * invN - mean * mean;
    const float r = 1.0f / sqrtf(var + BNEPS);
    const float scale = g[c] * r;
    sc[c] = scale;
    sh[c] = bb[c] - mean * scale;
}

__global__ __launch_bounds__(256) void apply_bn_kernel(const float* __restrict__ pre,
                                                       const float* __restrict__ sc,
                                                       const float* __restrict__ sh,
                                                       float* __restrict__ out)
{
    const size_t i = (size_t)blockIdx.x * 256 + threadIdx.x;
    const int c4 = (int)(i & 63);
    const float4 v = reinterpret_cast<const float4*>(pre)[i];
    const float4 s4 = reinterpret_cast<const float4*>(sc)[c4];
    const float4 b4 = reinterpret_cast<const float4*>(sh)[c4];
    float4 o;
    o.x = fmaf(v.x, s4.x, b4.x);
    o.y = fmaf(v.y, s4.y, b4.y);
    o.z = fmaf(v.z, s4.z, b4.z);
    o.w = fmaf(v.w, s4.w, b4.w);
    reinterpret_cast<float4*>(out)[i] = o;
}

// ---------------------------------------------------------------------------
// Launch. ws layout: h0 0-64Mi | A1 64-128Mi | A2 128-192Mi | pre 192-200Mi |
// fidx 200Mi | ps/pq/scv/sc3/sh3 201Mi | FusedSync 203Mi.
// ---------------------------------------------------------------------------
extern "C" void kernel_launch(void* const* d_in, const int* in_sizes, int n_in,
                              void* d_out, int out_size, void* d_ws, size_t ws_size,
                              hipStream_t stream)
{
    (void)in_sizes; (void)n_in; (void)out_size; (void)ws_size;
    const float* xyz     = (const float*)d_in[0];
    const float* points  = (const float*)d_in[1];
    const float* fc1_w   = (const float*)d_in[2];
    const float* fc1_b   = (const float*)d_in[3];
    const float* conv1_w = (const float*)d_in[4];
    const float* conv1_b = (const float*)d_in[5];
    const float* conv2_w = (const float*)d_in[6];
    const float* conv2_b = (const float*)d_in[7];
    const float* bn1_g   = (const float*)d_in[8];
    const float* bn1_b   = (const float*)d_in[9];
    const float* bn2_g   = (const float*)d_in[10];
    const float* bn2_b   = (const float*)d_in[11];
    const float* bn_g    = (const float*)d_in[12];
    const float* bn_b    = (const float*)d_in[13];

    float* out = (float*)d_out;
    float* newxyz = out;                       // [4,2048,3]
    float* outpts = out + (size_t)Bn * Sn * 3; // [4,2048,256]

    char* w = (char*)d_ws;
    float* h0   = (float*)(w);
    float* A1   = (float*)(w + (64ull << 20));
    float* A2   = (float*)(w + (128ull << 20));
    float* pre  = (float*)(w + (192ull << 20));
    int*   fidx = (int*)  (w + (200ull << 20));
    float* ps   = (float*)(w + (201ull << 20));
    float* pq   = ps + 256 * 256;
    float* scv  = pq + 256 * 256;              // sc1,sh1,sc2,sh2 [4][256]
    float* sc3  = scv + 1024;
    float* sh3  = sc3 + 256;
    FusedSync* sync = (FusedSync*)(w + (203ull << 20));

    fps_zero_kernel<<<1, 64, 0, stream>>>((unsigned*)sync);
    fused_kernel<<<NBLK, 1024, 0, stream>>>(
        xyz, points, fc1_w, fc1_b, conv1_w, conv1_b, conv2_w, conv2_b,
        bn1_g, bn1_b, bn2_g, bn2_b, h0, A1, A2, pre, fidx, ps, pq, scv,
        newxyz, sync);
    stats_partial<<<64, 256, 0, stream>>>(pre, SROWS / 64, ps, pq);
    bn_finalize<<<1, 256, 0, stream>>>(ps, pq, 64, 1.0f / SROWS, bn_g, bn_b, sc3, sh3);
    apply_bn_kernel<<<(SROWS * DIMn / 4) / 256, 256, 0, stream>>>(pre, sc3, sh3, outpts);
}

// Round 12
// 3825.063 us; speedup vs baseline: 1.0774x; 1.0001x over previous
//
#include <hip/hip_runtime.h>
#include <math.h>

// Problem constants (fixed by setup_inputs)
#define Bn   4
#define Nn   16384
#define CINn 32
#define DIMn 256
#define Sn   2048
#define KNEI 16
#define BNEPS 1e-5f
#define MROWS (Bn * Nn)   // 65536
#define SROWS (Bn * Sn)   // 8192

#define NWORK 248                 // worker blocks
#define NBLK  (NWORK + Bn)        // 252 total blocks (<=256 CUs, 1/CU via LDS)

typedef float f32x2 __attribute__((ext_vector_type(2)));

struct FusedSync {
    unsigned stage[12];           // stage completion counters (workers)
    unsigned prog[Bn];            // FPS progress per batch (multiples of 64)
};

// ---------------------------------------------------------------------------
// DPP max helpers (VALU pipe). Identity 0 valid: reduced values >= 0.
// ---------------------------------------------------------------------------
#define UMAX_DPP(v, ctl, rmask)                                               \
    {                                                                         \
        unsigned _o = (unsigned)__builtin_amdgcn_update_dpp(                  \
            0, (int)(v), (ctl), (rmask), 0xf, true);                          \
        (v) = ((v) > _o) ? (v) : _o;                                          \
    }
#define WAVE_UMAX64(v)                                                        \
    UMAX_DPP(v, 0x111, 0xf) UMAX_DPP(v, 0x112, 0xf) UMAX_DPP(v, 0x114, 0xf)  \
    UMAX_DPP(v, 0x118, 0xf) UMAX_DPP(v, 0x142, 0xa) UMAX_DPP(v, 0x143, 0xc)
#define U64MAX_DPP16(khi, klo, ctl)                                           \
    {                                                                         \
        unsigned _lo2 = (unsigned)__builtin_amdgcn_update_dpp(                \
            0, (int)(klo), (ctl), 0xf, 0xf, true);                            \
        unsigned _hi2 = (unsigned)__builtin_amdgcn_update_dpp(                \
            0, (int)(khi), (ctl), 0xf, 0xf, true);                            \
        const bool _g = (_hi2 > (khi)) || (_hi2 == (khi) && _lo2 > (klo));    \
        (khi) = _g ? _hi2 : (khi);                                            \
        (klo) = _g ? _lo2 : (klo);                                            \
    }

__global__ __launch_bounds__(64) void fps_zero_kernel(unsigned* __restrict__ s)
{
    if (threadIdx.x < 16) s[threadIdx.x] = 0u;
}

// ---------------------------------------------------------------------------
// 64x64 GEMM tile computed by one 256-thread team (4 teams per 1024-block).
// Barrier counts uniform across teams (act guards data ops only).
// ---------------------------------------------------------------------------
template <bool BT, bool AFF>
__device__ void gemm_team(const float* A, const float* Bm, const float* bias,
                          const float* asc, const float* ash, float* C,
                          int K, int tile, bool act, float* lAs, float* lBs,
                          int ts)
{
    const int tx = ts & 15;
    const int ty = ts >> 4;
    const int r0 = (tile >> 2) * 64;
    const int c0 = (tile & 3) * 64;
    const int rrA = ts >> 2;
    const int kkA = (ts & 3) * 4;
    float acc[4][4] = {};
    for (int kc = 0; kc < K; kc += 16) {
        if (act) {
            const float4 v = *reinterpret_cast<const float4*>(
                &A[(size_t)(r0 + rrA) * K + kc + kkA]);
            const float vv[4] = {v.x, v.y, v.z, v.w};
#pragma unroll
            for (int m = 0; m < 4; ++m) {
                float xv = vv[m];
                if (AFF) {
                    const int k = kc + kkA + m;
                    xv = fmaxf(fmaf(xv, asc[k], ash[k]), 0.0f);
                }
                lAs[(kkA + m) * 64 + rrA] = xv;
            }
            if (BT) {
                const float4 u = *reinterpret_cast<const float4*>(
                    &Bm[(size_t)(c0 + rrA) * K + kc + kkA]);
                lBs[(kkA + 0) * 64 + rrA] = u.x;
                lBs[(kkA + 1) * 64 + rrA] = u.y;
                lBs[(kkA + 2) * 64 + rrA] = u.z;
                lBs[(kkA + 3) * 64 + rrA] = u.w;
            } else {
                const int kk = ts >> 4;
                const int cc = (ts & 15) * 4;
                const float4 u = *reinterpret_cast<const float4*>(
                    &Bm[(size_t)(kc + kk) * DIMn + c0 + cc]);
                *reinterpret_cast<float4*>(&lBs[kk * 64 + cc]) = u;
            }
        }
        __syncthreads();
        if (act) {
#pragma unroll
            for (int kk = 0; kk < 16; ++kk) {
                const float4 a = *reinterpret_cast<const float4*>(&lAs[kk * 64 + ty * 4]);
                const float4 bv = *reinterpret_cast<const float4*>(&lBs[kk * 64 + tx * 4]);
                const float av[4] = {a.x, a.y, a.z, a.w};
                const float bw[4] = {bv.x, bv.y, bv.z, bv.w};
#pragma unroll
                for (int i = 0; i < 4; ++i)
#pragma unroll
                    for (int j = 0; j < 4; ++j)
                        acc[i][j] = fmaf(av[i], bw[j], acc[i][j]);
            }
        }
        __syncthreads();
    }
    if (act) {
        const int c = c0 + tx * 4;
#pragma unroll
        for (int i = 0; i < 4; ++i) {
            float4 o;
            o.x = acc[i][0] + bias[c + 0];
            o.y = acc[i][1] + bias[c + 1];
            o.z = acc[i][2] + bias[c + 2];
            o.w = acc[i][3] + bias[c + 3];
            *reinterpret_cast<float4*>(&C[(size_t)(r0 + ty * 4 + i) * DIMn + c]) = o;
        }
    }
}

__device__ inline void stage_sync(unsigned* ctr, int t)
{
    __syncthreads();
    if (t == 0) {
        __hip_atomic_fetch_add(ctr, 1u, __ATOMIC_RELEASE, __HIP_MEMORY_SCOPE_AGENT);
        while (__hip_atomic_load(ctr, __ATOMIC_ACQUIRE, __HIP_MEMORY_SCOPE_AGENT)
               < (unsigned)NWORK)
            __builtin_amdgcn_s_sleep(2);
    }
    __syncthreads();
}

// ---------------------------------------------------------------------------
// Fused kernel. Blocks 0..3: FPS v10 -- 8 WORKING waves (t<512, 32 pts/thread
// as 16 packed pairs), 8 parked waves only execute barriers (uniform counts).
// Halves the redundant cross-wave tail + barrier skew vs v9's 16 waves and
// doubles per-thread ILP for LDS-latency hiding. Zero global accesses in the
// loop (winner z pushed via ballot+shfl to LDS); outputs ring-buffered (64)
// and flushed with a prog release every 64 samples.
// Blocks 4..251: h-chain (8 stage syncs), per-query gather+topk streamed
// behind FPS progress, then the FINAL BN fused in (stages 9-11).
// Selection numerics bit-identical to reference everywhere.
// ---------------------------------------------------------------------------
__global__ __launch_bounds__(1024, 1) void fused_kernel(
    const float* __restrict__ xyz, const float* __restrict__ points,
    const float* __restrict__ fc1_w, const float* __restrict__ fc1_b,
    const float* __restrict__ conv1_w, const float* __restrict__ conv1_b,
    const float* __restrict__ conv2_w, const float* __restrict__ conv2_b,
    const float* __restrict__ bn1_g, const float* __restrict__ bn1_b,
    const float* __restrict__ bn2_g, const float* __restrict__ bn2_b,
    const float* __restrict__ bn3_g, const float* __restrict__ bn3_b,
    float* __restrict__ h0, float* __restrict__ A1, float* __restrict__ A2,
    float* __restrict__ pre, int* __restrict__ fidx,
    float* __restrict__ ps, float* __restrict__ pq, float* __restrict__ scv,
    float* __restrict__ newxyz, float* __restrict__ outpts, FusedSync* sync)
{
    __shared__ __align__(16) char smem[131072];     // fps xy-pairs / topk keys / gemm
    __shared__ unsigned long long s_aux[33];        // fps s_wk[2][8] / topk wred+win
    __shared__ float s_wz[2][8];                    // fps per-wave winner z (parity)
    __shared__ __align__(16) float4 s_obuf[64];     // fps output ring (1KB)
    __shared__ int s_nidx[KNEI];
    const int t = threadIdx.x;

    if (blockIdx.x < Bn) {
        // ================= FPS path v10 =================
#pragma clang fp contract(off)
        float4* s_xy4 = reinterpret_cast<float4*>(smem);   // [8192] (x0,x1,y0,y1)
        unsigned long long (*s_wk)[8] =
            reinterpret_cast<unsigned long long (*)[8]>(s_aux);
        const int b = blockIdx.x;
        const int w = t >> 6;
        const int lane = t & 63;
        const bool act = t < 512;                   // 8 working waves
        const float* __restrict__ px = xyz + (size_t)b * Nn * 3;
        f32x2 z2[16], dist2[16];
        float cx = px[0], cy = px[1], cz = px[2];
        if (act) {
            // pair u = jp*512 + t owns points 2u, 2u+1
#pragma unroll
            for (int jp = 0; jp < 16; ++jp) {
                const int u = jp * 512 + t;
                const float2 q0 = *reinterpret_cast<const float2*>(&px[6 * u + 0]);
                const float2 q1 = *reinterpret_cast<const float2*>(&px[6 * u + 2]);
                const float2 q2 = *reinterpret_cast<const float2*>(&px[6 * u + 4]);
                float4 pk; pk.x = q0.x; pk.y = q1.y; pk.z = q0.y; pk.w = q2.x;
                s_xy4[u] = pk;                                   // (x0,x1,y0,y1)
                z2[jp] = f32x2{q1.x, q2.y};
                dist2[jp] = f32x2{__builtin_huge_valf(), __builtin_huge_valf()};
            }
#pragma unroll
            for (int p = 0; p < 16; ++p) asm volatile("" : "+v"(z2[p]));
        }
        if (t == 0) {
            float4 o0; o0.x = cx; o0.y = cy; o0.z = cz; o0.w = __int_as_float(0);
            s_obuf[0] = o0;
        }
        __syncthreads();
        for (int i = 0; i < Sn - 1; ++i) {
            if (act) {
                const f32x2 cx2 = {cx, cx}, cy2 = {cy, cy}, cz2 = {cz, cz};
                // ---- packed update of 16 pairs (x,y LDS, z VGPR) ----
                float bd = -1.0f;
#pragma unroll
                for (int jp = 0; jp < 16; ++jp) {
                    const float4 q = s_xy4[jp * 512 + t];
                    const f32x2 dx = f32x2{q.x, q.y} - cx2;
                    const f32x2 dy = f32x2{q.z, q.w} - cy2;
                    const f32x2 dz = z2[jp] - cz2;
                    const f32x2 dd = (dx * dx + dy * dy) + dz * dz;  // no fma
                    const float n0 = fminf(dist2[jp].x, dd.x);
                    const float n1 = fminf(dist2[jp].y, dd.y);
                    dist2[jp] = f32x2{n0, n1};
                    bd = fmaxf(bd, fmaxf(n0, n1));
                }
                // arg + z recovery: smallest n matching bd (descending n scan)
                unsigned bn = 0;
                float zb = 0.0f;
#pragma unroll
                for (int jp = 15; jp >= 0; --jp) {
                    const unsigned n0 = 2u * (unsigned)(jp * 512 + t);
                    if (dist2[jp].y == bd) { bn = 0xFFFFFFFFu - (n0 + 1); zb = z2[jp].y; }
                    if (dist2[jp].x == bd) { bn = 0xFFFFFFFFu - n0;       zb = z2[jp].x; }
                }
                // ---- wave reduce via DPP (nonneg f32 bits ~ u32 order) ----
                const unsigned bdu = __float_as_uint(bd);
                unsigned m = bdu;
                WAVE_UMAX64(m)
                const unsigned bdw = (unsigned)__builtin_amdgcn_readlane((int)m, 63);
                unsigned q2 = (bdu == bdw) ? bn : 0u;
                WAVE_UMAX64(q2)
                const unsigned bnw = (unsigned)__builtin_amdgcn_readlane((int)q2, 63);
                // winner lane's z (unique: bn embeds n)
                const unsigned long long wmask = __ballot(bdu == bdw && bn == bnw);
                const int wl = __ffsll((unsigned long long)wmask) - 1;
                const float zw = __shfl(zb, wl);
                if (lane == 0) {
                    s_wk[i & 1][w] = ((unsigned long long)bdw << 32) | bnw;
                    s_wz[i & 1][w] = zw;
                }
            }
            __syncthreads();
            if (act) {
                // ---- cross-wave: 8 entries, u64 DPP max in lanes 0..7 ----
                const unsigned long long kk = (lane < 8) ? s_wk[i & 1][lane] : 0ull;
                unsigned klo = (unsigned)kk;
                unsigned khi = (unsigned)(kk >> 32);
                U64MAX_DPP16(khi, klo, 0x111)
                U64MAX_DPP16(khi, klo, 0x112)
                U64MAX_DPP16(khi, klo, 0x114)
                const unsigned bnf = (unsigned)__builtin_amdgcn_readlane((int)klo, 7);
                const int wu = (int)(0xFFFFFFFFu - bnf);
                const int up = wu >> 1;                 // pair index
                const int ww = (up & 511) >> 6;         // owner wave
                const float4 qw = s_xy4[up];            // uniform LDS read
                cx = (wu & 1) ? qw.y : qw.x;
                cy = (wu & 1) ? qw.w : qw.z;
                cz = s_wz[i & 1][ww];                   // from owner wave (LDS)
                if (t == 0) {
                    float4 ob; ob.x = cx; ob.y = cy; ob.z = cz;
                    ob.w = __int_as_float(wu);
                    s_obuf[(i + 1) & 63] = ob;
                }
            }
            // ---- flush ring + publish progress every 64 samples ----
            if (((i + 2) & 63) == 0) {
                __syncthreads();                        // ring writes visible
                const int cb = (i + 1) - 63;
                if (t < 64) {
                    const float4 v = s_obuf[t];
                    const int bs = b * Sn + cb + t;
                    newxyz[(size_t)bs * 3 + 0] = v.x;
                    newxyz[(size_t)bs * 3 + 1] = v.y;
                    newxyz[(size_t)bs * 3 + 2] = v.z;
                    fidx[bs] = __float_as_int(v.w);
                }
                __syncthreads();                        // flush stores drained
                if (t == 0)
                    __hip_atomic_store(&sync->prog[b], (unsigned)(i + 2),
                                       __ATOMIC_RELEASE, __HIP_MEMORY_SCOPE_AGENT);
            }
        }
        return;
    }

    // ======================= worker path =======================
    const int wid = blockIdx.x - Bn;
    const int team = t >> 8;
    const int ts = t & 255;
    float* lAs = reinterpret_cast<float*>(smem) + team * 2048;
    float* lBs = lAs + 1024;
    float* sc1 = scv, *sh1 = scv + 256, *sc2 = scv + 512, *sh2 = scv + 768;
    float* sc3 = scv + 1024, *sh3 = scv + 1280;

    // S0: fc1 -> h0 (K=32). 4096 tiles over 992 teams, 5 uniform iters.
    for (int it = 0; it < 5; ++it) {
        const int tile = it * (NWORK * 4) + wid * 4 + team;
        gemm_team<false, false>(points, fc1_w, fc1_b, nullptr, nullptr, h0,
                                CINn, tile, tile < 4096, lAs, lBs, ts);
    }
    stage_sync(&sync->stage[0], t);
    // S1: conv1 -> A1 (K=256)
    for (int it = 0; it < 5; ++it) {
        const int tile = it * (NWORK * 4) + wid * 4 + team;
        gemm_team<true, false>(h0, conv1_w, conv1_b, nullptr, nullptr, A1,
                               DIMn, tile, tile < 4096, lAs, lBs, ts);
    }
    stage_sync(&sync->stage[1], t);
    // S2: BN1 stats (slabs of 256 rows)
    for (int sb = wid; sb < 256; sb += NWORK) {
        if (t < DIMn) {
            float s = 0.0f, q = 0.0f;
            const size_t r0 = (size_t)sb * 256;
            for (int r = 0; r < 256; ++r) {
                const float v = A1[(r0 + r) * DIMn + t];
                s += v;
                q = fmaf(v, v, q);
            }
            ps[sb * DIMn + t] = s;
            pq[sb * DIMn + t] = q;
        }
    }
    stage_sync(&sync->stage[2], t);
    // S3: BN1 finalize (block 0)
    if (wid == 0 && t < DIMn) {
        float s = 0.0f, q = 0.0f;
        for (int i = 0; i < 256; ++i) { s += ps[i * DIMn + t]; q += pq[i * DIMn + t]; }
        const float invN = 1.0f / MROWS;
        const float mean = s * invN;
        const float var = q * invN - mean * mean;
        const float r = 1.0f / sqrtf(var + BNEPS);
        const float scale = bn1_g[t] * r;
        sc1[t] = scale;
        sh1[t] = bn1_b[t] - mean * scale;
    }
    stage_sync(&sync->stage[3], t);
    // S4: conv2 -> A2 (BN1+relu fused into A-load)
    for (int it = 0; it < 5; ++it) {
        const int tile = it * (NWORK * 4) + wid * 4 + team;
        gemm_team<true, true>(A1, conv2_w, conv2_b, sc1, sh1, A2,
                              DIMn, tile, tile < 4096, lAs, lBs, ts);
    }
    stage_sync(&sync->stage[4], t);
    // S5: BN2 stats
    for (int sb = wid; sb < 256; sb += NWORK) {
        if (t < DIMn) {
            float s = 0.0f, q = 0.0f;
            const size_t r0 = (size_t)sb * 256;
            for (int r = 0; r < 256; ++r) {
                const float v = A2[(r0 + r) * DIMn + t];
                s += v;
                q = fmaf(v, v, q);
            }
            ps[sb * DIMn + t] = s;
            pq[sb * DIMn + t] = q;
        }
    }
    stage_sync(&sync->stage[5], t);
    // S6: BN2 finalize
    if (wid == 0 && t < DIMn) {
        float s = 0.0f, q = 0.0f;
        for (int i = 0; i < 256; ++i) { s += ps[i * DIMn + t]; q += pq[i * DIMn + t]; }
        const float invN = 1.0f / MROWS;
        const float mean = s * invN;
        const float var = q * invN - mean * mean;
        const float r = 1.0f / sqrtf(var + BNEPS);
        const float scale = bn2_g[t] * r;
        sc2[t] = scale;
        sh2[t] = bn2_b[t] - mean * scale;
    }
    stage_sync(&sync->stage[6], t);
    // S7: h_final = h0 + relu(BN2(A2)) -> A2 (h0 preserved for points_ori)
    for (size_t idx = (size_t)wid * 1024 + t; idx < (size_t)MROWS * DIMn / 4;
         idx += (size_t)NWORK * 1024) {
        const int c4 = (int)(idx & 63);
        const float4 hv = reinterpret_cast<const float4*>(h0)[idx];
        float4 av = reinterpret_cast<float4*>(A2)[idx];
        const float4 s4 = reinterpret_cast<const float4*>(sc2)[c4];
        const float4 b4 = reinterpret_cast<const float4*>(sh2)[c4];
        av.x = hv.x + fmaxf(fmaf(av.x, s4.x, b4.x), 0.0f);
        av.y = hv.y + fmaxf(fmaf(av.y, s4.y, b4.y), 0.0f);
        av.z = hv.z + fmaxf(fmaf(av.z, s4.z, b4.z), 0.0f);
        av.w = hv.w + fmaxf(fmaf(av.w, s4.w, b4.w), 0.0f);
        reinterpret_cast<float4*>(A2)[idx] = av;
    }
    stage_sync(&sync->stage[7], t);

    // S8: per-query gather + 16-NN + maxpool, streamed behind FPS progress.
    {
#pragma clang fp contract(off)
        unsigned* s_key = reinterpret_cast<unsigned*>(smem);          // 64 KB
        const int b = wid & 3;
        const int w = t >> 6;
        const int lane = t & 63;
        const float* px = xyz + (size_t)b * Nn * 3;
        unsigned cprog = 0;
        for (int q = wid; q < SROWS; q += NWORK) {
            const int s = q >> 2;
            if (t == 0 && cprog < (unsigned)(s + 1)) {
                unsigned p;
                do {
                    p = __hip_atomic_load(&sync->prog[b], __ATOMIC_ACQUIRE,
                                          __HIP_MEMORY_SCOPE_AGENT);
                    if (p < (unsigned)(s + 1)) __builtin_amdgcn_s_sleep(8);
                } while (p < (unsigned)(s + 1));
                cprog = p;
            }
            __syncthreads();
            const int bs = b * Sn + s;
            const float qx = newxyz[(size_t)bs * 3 + 0];
            const float qy = newxyz[(size_t)bs * 3 + 1];
            const float qz = newxyz[(size_t)bs * 3 + 2];
            const float qq = (qx * qx + qy * qy) + qz * qz;
            unsigned long long mkey = ~0ull;
#pragma unroll 4
            for (int u = 0; u < 16; ++u) {
                const int n = t + (u << 10);
                const float bx = px[n * 3 + 0];
                const float by = px[n * 3 + 1];
                const float bz = px[n * 3 + 2];
                const float bb2 = (bx * bx + by * by) + bz * bz;
                const float ab = (qx * bx + qy * by) + qz * bz;
                const float d = (qq + bb2) - 2.0f * ab;   // exact reference formula
                unsigned u32 = __float_as_uint(d);
                u32 = ((int)u32 < 0) ? ~u32 : (u32 | 0x80000000u);
                s_key[n] = u32;
                const unsigned long long k =
                    ((unsigned long long)u32 << 32) | (unsigned)n;
                mkey = (k < mkey) ? k : mkey;
            }
            __syncthreads();
            for (int r = 0; r < KNEI; ++r) {
                unsigned long long k = mkey;
#pragma unroll
                for (int off = 32; off > 0; off >>= 1) {
                    const unsigned long long o = __shfl_xor(k, off);
                    k = (o < k) ? o : k;
                }
                if (lane == 0) s_aux[w] = k;
                __syncthreads();
                if (w == 0) {
                    unsigned long long kk = (lane < 16) ? s_aux[lane] : ~0ull;
#pragma unroll
                    for (int off = 8; off > 0; off >>= 1) {
                        const unsigned long long o = __shfl_xor(kk, off);
                        kk = (o < kk) ? o : kk;
                    }
                    if (lane == 0) {
                        s_aux[32] = kk;
                        s_nidx[r] = (int)(unsigned)(kk & 0xFFFFFFFFull);
                    }
                }
                __syncthreads();
                const unsigned long long wk = s_aux[32];
                if (wk == mkey) {
                    const int wn = (int)(unsigned)(wk & 0xFFFFFFFFull);
                    s_key[wn] = 0xFFFFFFFFu;
                    mkey = ~0ull;
#pragma unroll 4
                    for (int u = 0; u < 16; ++u) {
                        const int n = t + (u << 10);
                        const unsigned long long kk2 =
                            ((unsigned long long)s_key[n] << 32) | (unsigned)n;
                        mkey = (kk2 < mkey) ? kk2 : mkey;
                    }
                }
            }
            __syncthreads();
            if (t < DIMn) {
                const int fid = fidx[bs];
                const float po = h0[((size_t)b * Nn + fid) * DIMn + t];
                float m = -__builtin_huge_valf();
#pragma unroll
                for (int r = 0; r < KNEI; ++r) {
                    const int n = s_nidx[r];
                    m = fmaxf(m, A2[((size_t)b * Nn + n) * DIMn + t]);
                }
                pre[(size_t)bs * DIMn + t] = po + m;
            }
            __syncthreads();
        }
    }
    stage_sync(&sync->stage[8], t);

    // S9: final BN stats over pre [8192 x 256]: 64 slabs x 128 rows
    if (wid < 64 && t < DIMn) {
        float s = 0.0f, q = 0.0f;
        const size_t r0 = (size_t)wid * 128;
        for (int r = 0; r < 128; ++r) {
            const float v = pre[(r0 + r) * DIMn + t];
            s += v;
            q = fmaf(v, v, q);
        }
        ps[wid * DIMn + t] = s;
        pq[wid * DIMn + t] = q;
    }
    stage_sync(&sync->stage[9], t);
    // S10: final BN finalize
    if (wid == 0 && t < DIMn) {
        float s = 0.0f, q = 0.0f;
        for (int i = 0; i < 64; ++i) { s += ps[i * DIMn + t]; q += pq[i * DIMn + t]; }
        const float invN = 1.0f / SROWS;
        const float mean = s * invN;
        const float var = q * invN - mean * mean;
        const float r = 1.0f / sqrtf(var + BNEPS);
        const float scale = bn3_g[t] * r;
        sc3[t] = scale;
        sh3[t] = bn3_b[t] - mean * scale;
    }
    stage_sync(&sync->stage[10], t);
    // S11: apply final BN -> outpts
    for (size_t idx = (size_t)wid * 1024 + t; idx < (size_t)SROWS * DIMn / 4;
         idx += (size_t)NWORK * 1024) {
        const int c4 = (int)(idx & 63);
        const float4 v = reinterpret_cast<const float4*>(pre)[idx];
        const float4 s4 = reinterpret_cast<const float4*>(sc3)[c4];
        const float4 b4 = reinterpret_cast<const float4*>(sh3)[c4];
        float4 o;
        o.x = fmaf(v.x, s4.x, b4.x);
        o.y = fmaf(v.y, s4.y, b4.y);
        o.z = fmaf(v.z, s4.z, b4.z);
        o.w = fmaf(v.w, s4.w, b4.w);
        reinterpret_cast<float4*>(outpts)[idx] = o;
    }
}

// ---------------------------------------------------------------------------
// Launch. ws layout: h0 0-64Mi | A1 64-128Mi | A2 128-192Mi | pre 192-200Mi |
// fidx 200Mi | ps/pq/scv 201Mi | FusedSync 203Mi.
// ---------------------------------------------------------------------------
extern "C" void kernel_launch(void* const* d_in, const int* in_sizes, int n_in,
                              void* d_out, int out_size, void* d_ws, size_t ws_size,
                              hipStream_t stream)
{
    (void)in_sizes; (void)n_in; (void)out_size; (void)ws_size;
    const float* xyz     = (const float*)d_in[0];
    const float* points  = (const float*)d_in[1];
    const float* fc1_w   = (const float*)d_in[2];
    const float* fc1_b   = (const float*)d_in[3];
    const float* conv1_w = (const float*)d_in[4];
    const float* conv1_b = (const float*)d_in[5];
    const float* conv2_w = (const float*)d_in[6];
    const float* conv2_b = (const float*)d_in[7];
    const float* bn1_g   = (const float*)d_in[8];
    const float* bn1_b   = (const float*)d_in[9];
    const float* bn2_g   = (const float*)d_in[10];
    const float* bn2_b   = (const float*)d_in[11];
    const float* bn_g    = (const float*)d_in[12];
    const float* bn_b    = (const float*)d_in[13];

    float* out = (float*)d_out;
    float* newxyz = out;                       // [4,2048,3]
    float* outpts = out + (size_t)Bn * Sn * 3; // [4,2048,256]

    char* w = (char*)d_ws;
    float* h0   = (float*)(w);
    float* A1   = (float*)(w + (64ull << 20));
    float* A2   = (float*)(w + (128ull << 20));
    float* pre  = (float*)(w + (192ull << 20));
    int*   fidx = (int*)  (w + (200ull << 20));
    float* ps   = (float*)(w + (201ull << 20));
    float* pq   = ps + 256 * 256;
    float* scv  = pq + 256 * 256;              // sc1,sh1,sc2,sh2,sc3,sh3 [6][256]
    FusedSync* sync = (FusedSync*)(w + (203ull << 20));

    fps_zero_kernel<<<1, 64, 0, stream>>>((unsigned*)sync);
    fused_kernel<<<NBLK, 1024, 0, stream>>>(
        xyz, points, fc1_w, fc1_b, conv1_w, conv1_b, conv2_w, conv2_b,
        bn1_g, bn1_b, bn2_g, bn2_b, bn_g, bn_b, h0, A1, A2, pre, fidx,
        ps, pq, scv, newxyz, outpts, sync);
}